// Round 18
// baseline (193.117 us; speedup 1.0000x reference)
//
#include <hip/hip_runtime.h>
#include <math.h>

#define NN 50000
#define EE 1600000
#define FIN 128
#define FOUT 128   // HEADS*HID
#define NEG 0.2f
#define BNEPS 1e-5f

#define NPART 8
#define PSZ (NN / NPART)   // 6250

#define BEB 1024           // edges per bucket block (4 per thread)
#define NBUCK ((EE + BEB - 1) / BEB)   // 1563
#define GGRP 8             // writer groups (one private region per (group,partition))
#define BCAPG 30000        // capacity per (group,partition) region (mean 25k)
#define DSUB 8             // deg sub-blocks per partition (== GGRP)

// float -> bf16 (round-to-nearest-even), returns low-16
static __device__ __forceinline__ unsigned f2bf(float f) {
  unsigned int u = __float_as_uint(f);
  u += 0x7fffu + ((u >> 16) & 1u);
  return u >> 16;
}

// ---------------- conv1 projection + attention logits (register-tiled GEMM) ----------------
// x tile staged as bf16 in LDS (16.9 KB -> 8 blocks/CU, double the latency cover).
// h stored int8 with per-row scale.
#define XSS 66   // u32 stride per row: 64 bf16-pairs + 2 pad (keeps 8B align, distinct banks)
__global__ __launch_bounds__(256) void k_proj(const float* __restrict__ x,
    const float* __restrict__ W1, const float* __restrict__ asw, const float* __restrict__ adw,
    signed char* __restrict__ h8, float* __restrict__ hscale,
    float* __restrict__ as1, float* __restrict__ ad1) {
  __shared__ unsigned xs[64 * XSS];
  int t = threadIdx.x;
  int nb = blockIdx.x * 64;

  #pragma unroll
  for (int j = 0; j < 8; ++j) {
    int idx = t + 256 * j;
    int r = idx >> 5;
    int c4 = idx & 31;
    int n = nb + r; if (n >= NN) n = NN - 1;
    float4 v = *(const float4*)(x + (size_t)n * FIN + c4 * 4);
    xs[r * XSS + c4 * 2]     = f2bf(v.x) | (f2bf(v.y) << 16);
    xs[r * XSS + c4 * 2 + 1] = f2bf(v.z) | (f2bf(v.w) << 16);
  }
  __syncthreads();

  int cg = t & 15;
  int ng = t >> 4;
  int c0 = cg * 8;

  float acc[4][8];
  #pragma unroll
  for (int i = 0; i < 4; ++i)
    #pragma unroll
    for (int j = 0; j < 8; ++j) acc[i][j] = 0.f;

  for (int k0 = 0; k0 < FIN; k0 += 4) {
    float xr[4][4];
    #pragma unroll
    for (int i = 0; i < 4; ++i) {
      uint2 u = *(const uint2*)&xs[(ng * 4 + i) * XSS + (k0 >> 1)];
      xr[i][0] = __uint_as_float(u.x << 16);
      xr[i][1] = __uint_as_float(u.x & 0xffff0000u);
      xr[i][2] = __uint_as_float(u.y << 16);
      xr[i][3] = __uint_as_float(u.y & 0xffff0000u);
    }
    #pragma unroll
    for (int kk = 0; kk < 4; ++kk) {
      float4 w0 = *(const float4*)(W1 + (k0 + kk) * FOUT + c0);
      float4 w1 = *(const float4*)(W1 + (k0 + kk) * FOUT + c0 + 4);
      float wv[8] = {w0.x, w0.y, w0.z, w0.w, w1.x, w1.y, w1.z, w1.w};
      #pragma unroll
      for (int i = 0; i < 4; ++i) {
        float xv = xr[i][kk];
        #pragma unroll
        for (int j = 0; j < 8; ++j) acc[i][j] = fmaf(xv, wv[j], acc[i][j]);
      }
    }
  }

  int head = cg >> 2;
  float vs[4], vd[4], rmax[4];
  #pragma unroll
  for (int i = 0; i < 4; ++i) {
    float s = 0.f, d = 0.f, m = 0.f;
    #pragma unroll
    for (int j = 0; j < 8; ++j) {
      s = fmaf(acc[i][j], asw[c0 + j], s);
      d = fmaf(acc[i][j], adw[c0 + j], d);
      m = fmaxf(m, fabsf(acc[i][j]));
    }
    vs[i] = s; vd[i] = d; rmax[i] = m;
  }
  #pragma unroll
  for (int i = 0; i < 4; ++i) {
    rmax[i] = fmaxf(rmax[i], __shfl_xor(rmax[i], 1, 64));
    rmax[i] = fmaxf(rmax[i], __shfl_xor(rmax[i], 2, 64));
    rmax[i] = fmaxf(rmax[i], __shfl_xor(rmax[i], 4, 64));
    rmax[i] = fmaxf(rmax[i], __shfl_xor(rmax[i], 8, 64));
  }
  #pragma unroll
  for (int i = 0; i < 4; ++i) {
    int n = nb + ng * 4 + i;
    if (n >= NN) continue;
    float rm = fmaxf(rmax[i], 1e-30f);
    float inv = 127.f / rm;
    unsigned b[8];
    #pragma unroll
    for (int j = 0; j < 8; ++j) {
      float qf = fminf(127.f, fmaxf(-127.f, rintf(acc[i][j] * inv)));
      b[j] = (unsigned)((int)qf) & 0xffu;
    }
    uint2 pk;
    pk.x = b[0] | (b[1] << 8) | (b[2] << 16) | (b[3] << 24);
    pk.y = b[4] | (b[5] << 8) | (b[6] << 16) | (b[7] << 24);
    *(uint2*)(h8 + (size_t)n * FOUT + c0) = pk;
    if (cg == 0) hscale[n] = rm / 127.f;
  }
  #pragma unroll
  for (int i = 0; i < 4; ++i) {
    vs[i] += __shfl_xor(vs[i], 1, 64); vs[i] += __shfl_xor(vs[i], 2, 64);
    vd[i] += __shfl_xor(vd[i], 1, 64); vd[i] += __shfl_xor(vd[i], 2, 64);
  }
  if ((cg & 3) == 0) {
    #pragma unroll
    for (int i = 0; i < 4; ++i) {
      int n = nb + ng * 4 + i;
      if (n < NN) { as1[n * 4 + head] = vs[i]; ad1[n * 4 + head] = vd[i]; }
    }
  }
}

// pass A: bucket edges by dst-range. 64 private regions (g,p).
__global__ __launch_bounds__(256) void k_bucket(const int* __restrict__ ei,
    int* __restrict__ bcur, unsigned* __restrict__ bkt) {
  __shared__ int lcnt[NPART];
  __shared__ int gbase[NPART];
  int t = threadIdx.x;
  int g = blockIdx.x & (GGRP - 1);
  if (t < NPART) lcnt[t] = 0;
  __syncthreads();
  int e0 = blockIdx.x * BEB;
  int part[4]; int lslot[4]; unsigned pk[4];
  #pragma unroll
  for (int j = 0; j < 4; ++j) {
    int i = e0 + j * 256 + t;
    if (i < EE) {
      int s = ei[i];
      int d = ei[EE + i];
      int p = d / PSZ;
      part[j] = p;
      pk[j] = (unsigned)s | ((unsigned)(d - p * PSZ) << 17);
      lslot[j] = atomicAdd(&lcnt[p], 1);
    } else part[j] = -1;
  }
  __syncthreads();
  if (t < NPART) gbase[t] = atomicAdd(&bcur[(g * NPART + t) * 16], lcnt[t]);
  __syncthreads();
  #pragma unroll
  for (int j = 0; j < 4; ++j) {
    if (part[j] >= 0)
      bkt[(size_t)(g * NPART + part[j]) * BCAPG + gbase[part[j]] + lslot[j]] = pk[j];
  }
}

// degree: block (g,p) LDS-histograms region (g,p). No global atomics.
__global__ __launch_bounds__(1024) void k_deg(const int* __restrict__ bcur,
    const unsigned* __restrict__ bkt, int* __restrict__ degp) {
  __shared__ int lh[PSZ];               // 25 KB
  int t = threadIdx.x;
  int part = blockIdx.x & (NPART - 1);
  int g    = blockIdx.x >> 3;
  for (int i = t; i < PSZ; i += 1024) lh[i] = 0;
  __syncthreads();
  int cnt = bcur[(g * NPART + part) * 16];
  const unsigned* b = bkt + (size_t)(g * NPART + part) * BCAPG;
  for (int i = t; i < cnt; i += 1024)
    atomicAdd(&lh[b[i] >> 17], 1);
  __syncthreads();
  int* dst = degp + ((size_t)part * DSUB + g) * PSZ;
  for (int i = t; i < PSZ; i += 1024) dst[i] = lh[i];
}

// Fused scan + scatter: block (g,p) computes partition base from bcur, the
// within-partition node prefix (chunked + block scan), writes offs (g==0 only),
// seeds lcur = offs + prefix_{g'<g} degp, places its region's edges, and (g==7)
// appends self-loops. Zero global atomics; single-writer csr lines per partition.
__global__ __launch_bounds__(1024) void k_scat4(const int* __restrict__ bcur,
    const unsigned* __restrict__ bkt, const int* __restrict__ degp,
    int* __restrict__ offs, int* __restrict__ csr) {
  __shared__ int lcur[PSZ];             // 25 KB
  __shared__ int sums[1024];
  __shared__ int sb[GGRP * NPART];
  int t = threadIdx.x;
  int p = blockIdx.x & (NPART - 1);
  int g = blockIdx.x >> 3;
  if (t < GGRP * NPART) sb[t] = bcur[t * 16];
  __syncthreads();

  int base_p = 0;
  for (int pp = 0; pp < p; ++pp) {
    int s = PSZ;
    for (int gg = 0; gg < GGRP; ++gg) s += sb[gg * NPART + pp];
    base_p += s;
  }

  const int CH = 7;                     // ceil(6250/1024)
  int n0 = t * CH;
  int tsum = 0;
  for (int i = 0; i < CH; ++i) {
    int idx = n0 + i;
    if (idx < PSZ) {
      int v = 1;
      for (int gg = 0; gg < GGRP; ++gg)
        v += degp[((size_t)p * DSUB + gg) * PSZ + idx];
      tsum += v;
    }
  }
  sums[t] = tsum; __syncthreads();
  for (int off = 1; off < 1024; off <<= 1) {
    int u = (t >= off) ? sums[t - off] : 0;
    __syncthreads();
    sums[t] += u;
    __syncthreads();
  }
  int run = base_p + ((t == 0) ? 0 : sums[t - 1]);
  for (int i = 0; i < CH; ++i) {
    int idx = n0 + i;
    if (idx < PSZ) {
      int v = 1, pre = 0;
      for (int gg = 0; gg < GGRP; ++gg) {
        int d = degp[((size_t)p * DSUB + gg) * PSZ + idx];
        v += d;
        if (gg < g) pre += d;
      }
      if (g == 0) offs[p * PSZ + idx] = run;
      lcur[idx] = run + pre;
      run += v;
    }
  }
  if (g == 0 && p == NPART - 1 && t == 1023)
    offs[NN] = base_p + sums[1023];     // total = EE + NN
  __syncthreads();

  int cnt = sb[g * NPART + p];
  const unsigned* b = bkt + (size_t)(g * NPART + p) * BCAPG;
  for (int i = t; i < cnt; i += 1024) {
    unsigned v = b[i];
    int pos = atomicAdd(&lcur[v >> 17], 1);
    csr[pos] = (int)(v & 0x1ffffu);
  }
  if (g == DSUB - 1) {
    __syncthreads();
    for (int i = t; i < PSZ; i += 1024)
      csr[lcur[i]] = p * PSZ + i;       // self loop: last slot of each segment
  }
}

// ---------------- conv1 aggregation + BN + leaky + conv2 projection ----------------
// Half-split wave (32 sublanes x 4 int8 channels, 2 edges per body step).
// {src, weight} packed per (slot,head) -> single ds_read_b64 in the body.
__global__ __launch_bounds__(256) void k_agg1(
    const int* __restrict__ offs, const int* __restrict__ csr,
    const signed char* __restrict__ h8, const float* __restrict__ hscale,
    const float* __restrict__ as1, const float* __restrict__ ad1,
    const float* __restrict__ bias1, const float* __restrict__ gamma, const float* __restrict__ beta,
    const float* __restrict__ mean, const float* __restrict__ var,
    const float* __restrict__ W2, const float* __restrict__ asw2, const float* __restrict__ adw2,
    float* __restrict__ h2, float* __restrict__ as2, float* __restrict__ ad2) {
  __shared__ uint2 swlds[4][32][4];     // {s, w} per [wave][edge-slot][head]  (4 KB)
  int wid = threadIdx.x >> 6;
  int lane = threadIdx.x & 63;
  int n = blockIdx.x * 4 + wid;
  if (n >= NN) return;
  int r0 = offs[n], r1 = offs[n + 1];
  int l  = lane & 31;                  // sublane: channels 4l..4l+3
  int hf = lane >> 5;                  // half
  int hh = l >> 3;                     // head of this lane's channels
  const signed char* hpb = h8;
  float2 adv = *(const float2*)(ad1 + n * 4 + hf * 2);

  float acc0 = 0.f, acc1 = 0.f, acc2 = 0.f, acc3 = 0.f;
  float denp0 = 0.f, denp1 = 0.f;

#define AGG_PRE(IDX, PRED)                                         \
  {                                                                \
    int sv = csr[(IDX)];                                           \
    float hs = hscale[sv];                                         \
    float2 av = *(const float2*)(as1 + sv * 4 + hf * 2);           \
    float e0 = av.x + adv.x; e0 = e0 > 0.f ? e0 : NEG * e0;        \
    float e1 = av.y + adv.y; e1 = e1 > 0.f ? e1 : NEG * e1;        \
    float ex0 = __expf(e0), ex1 = __expf(e1);                      \
    if (PRED) { denp0 += ex0; denp1 += ex1; }                      \
    float w0 = (PRED) ? ex0 * hs : 0.f;                            \
    float w1 = (PRED) ? ex1 * hs : 0.f;                            \
    swlds[wid][l][hf * 2]     = make_uint2((unsigned)sv, __float_as_uint(w0)); \
    swlds[wid][l][hf * 2 + 1] = make_uint2((unsigned)sv, __float_as_uint(w1)); \
  }

#define AGG_BODY(J)                                                \
  {                                                                \
    uint2 sw = swlds[wid][hf * 16 + (J)][hh];                      \
    int s = (int)sw.x;                                             \
    float w = __uint_as_float(sw.y);                               \
    unsigned pv = *(const unsigned*)(hpb + (size_t)s * FOUT + l * 4); \
    int q0 = ((int)(pv << 24)) >> 24;                              \
    int q1 = ((int)(pv << 16)) >> 24;                              \
    int q2 = ((int)(pv << 8)) >> 24;                               \
    int q3 = ((int)pv) >> 24;                                      \
    acc0 = fmaf(w, (float)q0, acc0);                               \
    acc1 = fmaf(w, (float)q1, acc1);                               \
    acc2 = fmaf(w, (float)q2, acc2);                               \
    acc3 = fmaf(w, (float)q3, acc3);                               \
  }

  int base = r0;
  for (; base + 32 <= r1; base += 32) {
    AGG_PRE(base + l, true)
    #pragma unroll
    for (int j = 0; j < 16; ++j) AGG_BODY(j)
  }
  int m = r1 - base;
  if (m > 0) {
    AGG_PRE(base + (l < m ? l : m - 1), l < m)
    int jmax = m < 16 ? m : 16;
    for (int j = 0; j < jmax; ++j) AGG_BODY(j)
  }

  acc0 += __shfl_xor(acc0, 32, 64);
  acc1 += __shfl_xor(acc1, 32, 64);
  acc2 += __shfl_xor(acc2, 32, 64);
  acc3 += __shfl_xor(acc3, 32, 64);

  #pragma unroll
  for (int mm = 16; mm >= 1; mm >>= 1) {
    denp0 += __shfl_xor(denp0, mm, 64);
    denp1 += __shfl_xor(denp1, mm, 64);
  }
  float dOA = __shfl_xor(denp0, 32, 64);
  float dOB = __shfl_xor(denp1, 32, 64);
  float den0 = hf ? dOA : denp0;
  float den1 = hf ? dOB : denp1;
  float den2 = hf ? denp0 : dOA;
  float den3 = hf ? denp1 : dOB;
  float den = (hh == 0) ? den0 : (hh == 1) ? den1 : (hh == 2) ? den2 : den3;

  int c0 = l * 4;
  float inv = 1.f / den;
  float4 bi = *(const float4*)(bias1 + c0);
  float4 ga = *(const float4*)(gamma + c0);
  float4 be = *(const float4*)(beta + c0);
  float4 mu = *(const float4*)(mean + c0);
  float4 va = *(const float4*)(var + c0);
  float o0 = acc0 * inv + bi.x;
  float o1 = acc1 * inv + bi.y;
  float o2 = acc2 * inv + bi.z;
  float o3 = acc3 * inv + bi.w;
  o0 = ga.x * (o0 - mu.x) * rsqrtf(va.x + BNEPS) + be.x;
  o1 = ga.y * (o1 - mu.y) * rsqrtf(va.y + BNEPS) + be.y;
  o2 = ga.z * (o2 - mu.z) * rsqrtf(va.z + BNEPS) + be.z;
  o3 = ga.w * (o3 - mu.w) * rsqrtf(va.w + BNEPS) + be.w;
  o0 = o0 > 0.f ? o0 : NEG * o0;
  o1 = o1 > 0.f ? o1 : NEG * o1;
  o2 = o2 > 0.f ? o2 : NEG * o2;
  o3 = o3 > 0.f ? o3 : NEG * o3;

  float p0 = o0 * W2[(c0 + 0) * 2 + 0] + o1 * W2[(c0 + 1) * 2 + 0]
           + o2 * W2[(c0 + 2) * 2 + 0] + o3 * W2[(c0 + 3) * 2 + 0];
  float p1 = o0 * W2[(c0 + 0) * 2 + 1] + o1 * W2[(c0 + 1) * 2 + 1]
           + o2 * W2[(c0 + 2) * 2 + 1] + o3 * W2[(c0 + 3) * 2 + 1];
  #pragma unroll
  for (int mm = 16; mm >= 1; mm >>= 1) {
    p0 += __shfl_xor(p0, mm, 64);
    p1 += __shfl_xor(p1, mm, 64);
  }
  if (lane == 0) {
    h2[n * 2 + 0] = p0;
    h2[n * 2 + 1] = p1;
    as2[n] = p0 * asw2[0] + p1 * asw2[1];
    ad2[n] = p0 * adw2[0] + p1 * adw2[1];
  }
}

// ---------------- conv2 aggregation (no-max softmax) + bias + log_softmax ----------------
__global__ __launch_bounds__(256) void k_agg2(
    const int* __restrict__ offs, const int* __restrict__ csr,
    const float* __restrict__ h2, const float* __restrict__ as2, const float* __restrict__ ad2,
    const float* __restrict__ bias2, float* __restrict__ out) {
  int wid = threadIdx.x >> 6;
  int lane = threadIdx.x & 63;
  int n = blockIdx.x * 4 + wid;
  if (n >= NN) return;
  int r0 = offs[n], r1 = offs[n + 1];
  float ad = ad2[n];

  float den = 0.f, a0 = 0.f, a1 = 0.f;
  for (int i = r0 + lane; i < r1; i += 64) {
    int s = csr[i];
    float e = as2[s] + ad; e = e > 0.f ? e : NEG * e;
    float ex = __expf(e);
    float2 hv = *(const float2*)(h2 + s * 2);
    den += ex;
    a0 = fmaf(ex, hv.x, a0);
    a1 = fmaf(ex, hv.y, a1);
  }
  #pragma unroll
  for (int mm = 32; mm >= 1; mm >>= 1) {
    den += __shfl_xor(den, mm, 64);
    a0  += __shfl_xor(a0, mm, 64);
    a1  += __shfl_xor(a1, mm, 64);
  }
  if (lane == 0) {
    float o0 = a0 / den + bias2[0];
    float o1 = a1 / den + bias2[1];
    float mx = fmaxf(o0, o1);
    float lse = mx + logf(__expf(o0 - mx) + __expf(o1 - mx));
    out[n * 2 + 0] = o0 - lse;
    out[n * 2 + 1] = o1 - lse;
  }
}

extern "C" void kernel_launch(void* const* d_in, const int* in_sizes, int n_in,
                              void* d_out, int out_size, void* d_ws, size_t ws_size,
                              hipStream_t stream) {
  const float* x     = (const float*)d_in[0];
  const int*   ei    = (const int*)d_in[1];
  const float* W1    = (const float*)d_in[2];
  const float* asw1  = (const float*)d_in[3];
  const float* adw1  = (const float*)d_in[4];
  const float* bias1 = (const float*)d_in[5];
  const float* gamma = (const float*)d_in[6];
  const float* beta  = (const float*)d_in[7];
  const float* mean  = (const float*)d_in[8];
  const float* var   = (const float*)d_in[9];
  const float* W2    = (const float*)d_in[10];
  const float* asw2  = (const float*)d_in[11];
  const float* adw2  = (const float*)d_in[12];
  const float* bias2 = (const float*)d_in[13];
  float* out = (float*)d_out;

  char* ws = (char*)d_ws;
  size_t off = 0;
  auto alloc = [&](size_t bytes) {
    void* p = ws + off;
    off += (bytes + 255) & ~(size_t)255;
    return p;
  };
  signed char* h8 = (signed char*)alloc((size_t)NN * FOUT);   // 6.4 MB int8
  float* hscale = (float*)alloc((size_t)NN * 4);
  float* as1  = (float*)alloc((size_t)NN * 4 * 4);
  float* ad1  = (float*)alloc((size_t)NN * 4 * 4);
  int*   degp = (int*)alloc((size_t)NPART * DSUB * PSZ * 4);  // 1.6 MB partial histograms
  int*   offs = (int*)alloc(((size_t)NN + 1) * 4);
  int*   bcur = (int*)alloc((size_t)GGRP * NPART * 16 * 4);   // 64 padded counters
  int*   csr  = (int*)alloc((size_t)(EE + NN) * 4);           // 6.6 MB
  unsigned* bkt = (unsigned*)alloc((size_t)GGRP * NPART * BCAPG * 4); // 7.7 MB
  float* h2   = (float*)alloc((size_t)NN * 2 * 4);
  float* as2  = (float*)alloc((size_t)NN * 4);
  float* ad2  = (float*)alloc((size_t)NN * 4);
  (void)ws_size; (void)in_sizes; (void)n_in; (void)out_size;

  hipMemsetAsync(bcur, 0, (size_t)GGRP * NPART * 16 * 4, stream);
  k_proj   <<<(NN + 63) / 64, 256, 0, stream>>>(x, W1, asw1, adw1, h8, hscale, as1, ad1);
  k_bucket <<<NBUCK, 256, 0, stream>>>(ei, bcur, bkt);
  k_deg    <<<NPART * DSUB, 1024, 0, stream>>>(bcur, bkt, degp);
  k_scat4  <<<NPART * DSUB, 1024, 0, stream>>>(bcur, bkt, degp, offs, csr);
  k_agg1   <<<(NN + 3) / 4, 256, 0, stream>>>(offs, csr, h8, hscale, as1, ad1, bias1, gamma, beta,
                                              mean, var, W2, asw2, adw2, h2, as2, ad2);
  k_agg2   <<<(NN + 3) / 4, 256, 0, stream>>>(offs, csr, h2, as2, ad2, bias2, out);
}

// Round 19
// 169.059 us; speedup vs baseline: 1.1423x; 1.1423x over previous
//
#include <hip/hip_runtime.h>
#include <math.h>

#define NN 50000
#define EE 1600000
#define FIN 128
#define FOUT 128   // HEADS*HID
#define NEG 0.2f
#define BNEPS 1e-5f

#define NPART 8
#define PSZ (NN / NPART)   // 6250

#define SCB 49             // scan blocks (49*1024 >= 50000)
#define BEB 1024           // edges per bucket block (4 per thread)
#define NBUCK ((EE + BEB - 1) / BEB)   // 1563
#define GGRP 8             // writer groups (one private region per (group,partition))
#define BCAPG 30000        // capacity per (group,partition) region (mean 25k)
#define DSUB 8             // deg sub-blocks per partition (== GGRP)

// ---------------- conv1 projection + attention logits (register-tiled GEMM) ----------------
// h stored int8 with per-row scale: h[n][c] ~= q[n][c] * hscale[n].
#define XS_STRIDE 132
__global__ __launch_bounds__(256) void k_proj(const float* __restrict__ x,
    const float* __restrict__ W1, const float* __restrict__ asw, const float* __restrict__ adw,
    signed char* __restrict__ h8, float* __restrict__ hscale,
    float* __restrict__ as1, float* __restrict__ ad1) {
  __shared__ float xs[64 * XS_STRIDE];
  int t = threadIdx.x;
  int nb = blockIdx.x * 64;

  #pragma unroll
  for (int j = 0; j < 8; ++j) {
    int idx = t + 256 * j;
    int r = idx >> 5;
    int c4 = idx & 31;
    int n = nb + r; if (n >= NN) n = NN - 1;
    float4 v = *(const float4*)(x + (size_t)n * FIN + c4 * 4);
    *(float4*)(&xs[r * XS_STRIDE + c4 * 4]) = v;
  }
  __syncthreads();

  int cg = t & 15;
  int ng = t >> 4;
  int c0 = cg * 8;

  float acc[4][8];
  #pragma unroll
  for (int i = 0; i < 4; ++i)
    #pragma unroll
    for (int j = 0; j < 8; ++j) acc[i][j] = 0.f;

  for (int k0 = 0; k0 < FIN; k0 += 4) {
    float xr[4][4];
    #pragma unroll
    for (int i = 0; i < 4; ++i)
      *(float4*)xr[i] = *(const float4*)&xs[(ng * 4 + i) * XS_STRIDE + k0];
    #pragma unroll
    for (int kk = 0; kk < 4; ++kk) {
      float4 w0 = *(const float4*)(W1 + (k0 + kk) * FOUT + c0);
      float4 w1 = *(const float4*)(W1 + (k0 + kk) * FOUT + c0 + 4);
      float wv[8] = {w0.x, w0.y, w0.z, w0.w, w1.x, w1.y, w1.z, w1.w};
      #pragma unroll
      for (int i = 0; i < 4; ++i) {
        float xv = xr[i][kk];
        #pragma unroll
        for (int j = 0; j < 8; ++j) acc[i][j] = fmaf(xv, wv[j], acc[i][j]);
      }
    }
  }

  int head = cg >> 2;
  float vs[4], vd[4], rmax[4];
  #pragma unroll
  for (int i = 0; i < 4; ++i) {
    float s = 0.f, d = 0.f, m = 0.f;
    #pragma unroll
    for (int j = 0; j < 8; ++j) {
      s = fmaf(acc[i][j], asw[c0 + j], s);
      d = fmaf(acc[i][j], adw[c0 + j], d);
      m = fmaxf(m, fabsf(acc[i][j]));
    }
    vs[i] = s; vd[i] = d; rmax[i] = m;
  }
  #pragma unroll
  for (int i = 0; i < 4; ++i) {
    rmax[i] = fmaxf(rmax[i], __shfl_xor(rmax[i], 1, 64));
    rmax[i] = fmaxf(rmax[i], __shfl_xor(rmax[i], 2, 64));
    rmax[i] = fmaxf(rmax[i], __shfl_xor(rmax[i], 4, 64));
    rmax[i] = fmaxf(rmax[i], __shfl_xor(rmax[i], 8, 64));
  }
  #pragma unroll
  for (int i = 0; i < 4; ++i) {
    int n = nb + ng * 4 + i;
    if (n >= NN) continue;
    float rm = fmaxf(rmax[i], 1e-30f);
    float inv = 127.f / rm;
    unsigned b[8];
    #pragma unroll
    for (int j = 0; j < 8; ++j) {
      float qf = fminf(127.f, fmaxf(-127.f, rintf(acc[i][j] * inv)));
      b[j] = (unsigned)((int)qf) & 0xffu;
    }
    uint2 pk;
    pk.x = b[0] | (b[1] << 8) | (b[2] << 16) | (b[3] << 24);
    pk.y = b[4] | (b[5] << 8) | (b[6] << 16) | (b[7] << 24);
    *(uint2*)(h8 + (size_t)n * FOUT + c0) = pk;
    if (cg == 0) hscale[n] = rm / 127.f;
  }
  #pragma unroll
  for (int i = 0; i < 4; ++i) {
    vs[i] += __shfl_xor(vs[i], 1, 64); vs[i] += __shfl_xor(vs[i], 2, 64);
    vd[i] += __shfl_xor(vd[i], 1, 64); vd[i] += __shfl_xor(vd[i], 2, 64);
  }
  if ((cg & 3) == 0) {
    #pragma unroll
    for (int i = 0; i < 4; ++i) {
      int n = nb + ng * 4 + i;
      if (n < NN) { as1[n * 4 + head] = vs[i]; ad1[n * 4 + head] = vd[i]; }
    }
  }
}

// pass A: bucket edges by dst-range. 64 private regions (g,p).
__global__ __launch_bounds__(256) void k_bucket(const int* __restrict__ ei,
    int* __restrict__ bcur, unsigned* __restrict__ bkt) {
  __shared__ int lcnt[NPART];
  __shared__ int gbase[NPART];
  int t = threadIdx.x;
  int g = blockIdx.x & (GGRP - 1);
  if (t < NPART) lcnt[t] = 0;
  __syncthreads();
  int e0 = blockIdx.x * BEB;
  int part[4]; int lslot[4]; unsigned pk[4];
  #pragma unroll
  for (int j = 0; j < 4; ++j) {
    int i = e0 + j * 256 + t;
    if (i < EE) {
      int s = ei[i];
      int d = ei[EE + i];
      int p = d / PSZ;
      part[j] = p;
      pk[j] = (unsigned)s | ((unsigned)(d - p * PSZ) << 17);
      lslot[j] = atomicAdd(&lcnt[p], 1);
    } else part[j] = -1;
  }
  __syncthreads();
  if (t < NPART) gbase[t] = atomicAdd(&bcur[(g * NPART + t) * 16], lcnt[t]);
  __syncthreads();
  #pragma unroll
  for (int j = 0; j < 4; ++j) {
    if (part[j] >= 0)
      bkt[(size_t)(g * NPART + part[j]) * BCAPG + gbase[part[j]] + lslot[j]] = pk[j];
  }
}

// degree: block (g,p) LDS-histograms region (g,p). No global atomics.
__global__ __launch_bounds__(1024) void k_deg(const int* __restrict__ bcur,
    const unsigned* __restrict__ bkt, int* __restrict__ degp) {
  __shared__ int lh[PSZ];               // 25 KB
  int t = threadIdx.x;
  int part = blockIdx.x & (NPART - 1);
  int g    = blockIdx.x >> 3;
  for (int i = t; i < PSZ; i += 1024) lh[i] = 0;
  __syncthreads();
  int cnt = bcur[(g * NPART + part) * 16];
  const unsigned* b = bkt + (size_t)(g * NPART + part) * BCAPG;
  for (int i = t; i < cnt; i += 1024)
    atomicAdd(&lh[b[i] >> 17], 1);
  __syncthreads();
  int* dst = degp + ((size_t)part * DSUB + g) * PSZ;
  for (int i = t; i < PSZ; i += 1024) dst[i] = lh[i];
}

// scanA: deg(idx) = 1 (self loop) + sum of DSUB partial histograms
__global__ __launch_bounds__(1024) void k_scanA(const int* __restrict__ degp,
    int* __restrict__ cur, int* __restrict__ bsum) {
  __shared__ int sums[1024];
  int t = threadIdx.x;
  int idx = blockIdx.x * 1024 + t;
  int v = 0;
  if (idx < NN) {
    int p = idx / PSZ, l = idx - p * PSZ;
    v = 1;
    #pragma unroll
    for (int k = 0; k < DSUB; ++k)
      v += degp[((size_t)p * DSUB + k) * PSZ + l];
  }
  sums[t] = v; __syncthreads();
  #pragma unroll
  for (int off = 1; off < 1024; off <<= 1) {
    int u = (t >= off) ? sums[t - off] : 0;
    __syncthreads();
    sums[t] += u;
    __syncthreads();
  }
  if (idx < NN) cur[idx] = sums[t] - v;
  if (t == 1023) bsum[blockIdx.x] = sums[1023];
}

__global__ __launch_bounds__(1024) void k_scanB(const int* __restrict__ bsum,
    int* __restrict__ offs, int* __restrict__ cur) {
  int b = blockIdx.x;
  int t = threadIdx.x;
  int base = 0;
  for (int i = 0; i < SCB; ++i) base += (i < b) ? bsum[i] : 0;
  int idx = b * 1024 + t;
  if (idx < NN) {
    int v = cur[idx] + base;
    offs[idx] = v;
    cur[idx] = v;
  }
  if (b == SCB - 1 && t == 0) {
    int total = base;
    for (int i = b; i < SCB; ++i) total += bsum[i];
    offs[NN] = total;
  }
}

// pass B: deterministic scatter (zero global atomics, single-writer lines per partition).
__global__ __launch_bounds__(1024) void k_scat3(const int* __restrict__ bcur,
    const unsigned* __restrict__ bkt, const int* __restrict__ offs,
    const int* __restrict__ degp, int* __restrict__ csr) {
  __shared__ int lcur[PSZ];             // 25 KB
  int t = threadIdx.x;
  int p = blockIdx.x & (NPART - 1);
  int g = blockIdx.x >> 3;
  int nbase = p * PSZ;
  for (int i = t; i < PSZ; i += 1024) {
    int c = offs[nbase + i];
    for (int gp = 0; gp < g; ++gp)
      c += degp[((size_t)p * DSUB + gp) * PSZ + i];
    lcur[i] = c;
  }
  __syncthreads();
  int cnt = bcur[(g * NPART + p) * 16];
  const unsigned* b = bkt + (size_t)(g * NPART + p) * BCAPG;
  for (int i = t; i < cnt; i += 1024) {
    unsigned v = b[i];
    int pos = atomicAdd(&lcur[v >> 17], 1);
    csr[pos] = (int)(v & 0x1ffffu);
  }
  if (g == DSUB - 1) {
    __syncthreads();
    for (int i = t; i < PSZ; i += 1024)
      csr[lcur[i]] = nbase + i;
  }
}

// ---------------- conv1 aggregation + BN + leaky + conv2 projection ----------------
// Half-split wave: 32 sublanes x 4 int8 channels; two wave halves process two
// DIFFERENT edges per body step. slds stores PRE-MULTIPLIED byte row offset
// (s*FOUT) so the body gather address is one 32-bit add.
__global__ __launch_bounds__(256) void k_agg1(
    const int* __restrict__ offs, const int* __restrict__ csr,
    const signed char* __restrict__ h8, const float* __restrict__ hscale,
    const float* __restrict__ as1, const float* __restrict__ ad1,
    const float* __restrict__ bias1, const float* __restrict__ gamma, const float* __restrict__ beta,
    const float* __restrict__ mean, const float* __restrict__ var,
    const float* __restrict__ W2, const float* __restrict__ asw2, const float* __restrict__ adw2,
    float* __restrict__ h2, float* __restrict__ as2, float* __restrict__ ad2) {
  __shared__ int   slds[4][32];
  __shared__ float wlds[4][32][4];
  int wid = threadIdx.x >> 6;
  int lane = threadIdx.x & 63;
  int n = blockIdx.x * 4 + wid;
  if (n >= NN) return;
  int r0 = offs[n], r1 = offs[n + 1];
  int l  = lane & 31;                  // sublane: channels 4l..4l+3
  int hf = lane >> 5;                  // half
  int hh = l >> 3;                     // head of this lane's channels
  int l4 = l * 4;
  const signed char* hpb = h8;
  float2 adv = *(const float2*)(ad1 + n * 4 + hf * 2);

  float acc0 = 0.f, acc1 = 0.f, acc2 = 0.f, acc3 = 0.f;
  float denp0 = 0.f, denp1 = 0.f;

#define AGG_PRE(IDX, PRED)                                         \
  {                                                                \
    int sv = csr[(IDX)];                                           \
    float hs = hscale[sv];                                         \
    float2 av = *(const float2*)(as1 + sv * 4 + hf * 2);           \
    float e0 = av.x + adv.x; e0 = e0 > 0.f ? e0 : NEG * e0;        \
    float e1 = av.y + adv.y; e1 = e1 > 0.f ? e1 : NEG * e1;        \
    float ex0 = __expf(e0), ex1 = __expf(e1);                      \
    float w0 = ex0 * hs, w1 = ex1 * hs;                            \
    if (PRED) { denp0 += ex0; denp1 += ex1; }                      \
    wlds[wid][l][hf * 2]     = (PRED) ? w0 : 0.f;                  \
    wlds[wid][l][hf * 2 + 1] = (PRED) ? w1 : 0.f;                  \
    if (hf == 0) slds[wid][l] = sv * FOUT;                         \
  }

#define AGG_BODY(J)                                                \
  {                                                                \
    int soff = slds[wid][hf * 16 + (J)];                           \
    float w = wlds[wid][hf * 16 + (J)][hh];                        \
    unsigned pv = *(const unsigned*)(hpb + soff + l4);             \
    int q0 = ((int)(pv << 24)) >> 24;                              \
    int q1 = ((int)(pv << 16)) >> 24;                              \
    int q2 = ((int)(pv << 8)) >> 24;                               \
    int q3 = ((int)pv) >> 24;                                      \
    acc0 = fmaf(w, (float)q0, acc0);                               \
    acc1 = fmaf(w, (float)q1, acc1);                               \
    acc2 = fmaf(w, (float)q2, acc2);                               \
    acc3 = fmaf(w, (float)q3, acc3);                               \
  }

  int base = r0;
  for (; base + 32 <= r1; base += 32) {
    AGG_PRE(base + l, true)
    #pragma unroll
    for (int j = 0; j < 16; ++j) AGG_BODY(j)
  }
  int m = r1 - base;
  if (m > 0) {
    AGG_PRE(base + (l < m ? l : m - 1), l < m)
    int jmax = m < 16 ? m : 16;
    for (int j = 0; j < jmax; ++j) AGG_BODY(j)
  }

  acc0 += __shfl_xor(acc0, 32, 64);
  acc1 += __shfl_xor(acc1, 32, 64);
  acc2 += __shfl_xor(acc2, 32, 64);
  acc3 += __shfl_xor(acc3, 32, 64);

  #pragma unroll
  for (int mm = 16; mm >= 1; mm >>= 1) {
    denp0 += __shfl_xor(denp0, mm, 64);
    denp1 += __shfl_xor(denp1, mm, 64);
  }
  float dOA = __shfl_xor(denp0, 32, 64);
  float dOB = __shfl_xor(denp1, 32, 64);
  float den0 = hf ? dOA : denp0;
  float den1 = hf ? dOB : denp1;
  float den2 = hf ? denp0 : dOA;
  float den3 = hf ? denp1 : dOB;
  float den = (hh == 0) ? den0 : (hh == 1) ? den1 : (hh == 2) ? den2 : den3;

  int c0 = l * 4;
  float inv = 1.f / den;
  float4 bi = *(const float4*)(bias1 + c0);
  float4 ga = *(const float4*)(gamma + c0);
  float4 be = *(const float4*)(beta + c0);
  float4 mu = *(const float4*)(mean + c0);
  float4 va = *(const float4*)(var + c0);
  float o0 = acc0 * inv + bi.x;
  float o1 = acc1 * inv + bi.y;
  float o2 = acc2 * inv + bi.z;
  float o3 = acc3 * inv + bi.w;
  o0 = ga.x * (o0 - mu.x) * rsqrtf(va.x + BNEPS) + be.x;
  o1 = ga.y * (o1 - mu.y) * rsqrtf(va.y + BNEPS) + be.y;
  o2 = ga.z * (o2 - mu.z) * rsqrtf(va.z + BNEPS) + be.z;
  o3 = ga.w * (o3 - mu.w) * rsqrtf(va.w + BNEPS) + be.w;
  o0 = o0 > 0.f ? o0 : NEG * o0;
  o1 = o1 > 0.f ? o1 : NEG * o1;
  o2 = o2 > 0.f ? o2 : NEG * o2;
  o3 = o3 > 0.f ? o3 : NEG * o3;

  float p0 = o0 * W2[(c0 + 0) * 2 + 0] + o1 * W2[(c0 + 1) * 2 + 0]
           + o2 * W2[(c0 + 2) * 2 + 0] + o3 * W2[(c0 + 3) * 2 + 0];
  float p1 = o0 * W2[(c0 + 0) * 2 + 1] + o1 * W2[(c0 + 1) * 2 + 1]
           + o2 * W2[(c0 + 2) * 2 + 1] + o3 * W2[(c0 + 3) * 2 + 1];
  #pragma unroll
  for (int mm = 16; mm >= 1; mm >>= 1) {
    p0 += __shfl_xor(p0, mm, 64);
    p1 += __shfl_xor(p1, mm, 64);
  }
  if (lane == 0) {
    h2[n * 2 + 0] = p0;
    h2[n * 2 + 1] = p1;
    as2[n] = p0 * asw2[0] + p1 * asw2[1];
    ad2[n] = p0 * adw2[0] + p1 * adw2[1];
  }
}

// ---------------- conv2 aggregation (no-max softmax) + bias + log_softmax ----------------
__global__ __launch_bounds__(256) void k_agg2(
    const int* __restrict__ offs, const int* __restrict__ csr,
    const float* __restrict__ h2, const float* __restrict__ as2, const float* __restrict__ ad2,
    const float* __restrict__ bias2, float* __restrict__ out) {
  int wid = threadIdx.x >> 6;
  int lane = threadIdx.x & 63;
  int n = blockIdx.x * 4 + wid;
  if (n >= NN) return;
  int r0 = offs[n], r1 = offs[n + 1];
  float ad = ad2[n];

  float den = 0.f, a0 = 0.f, a1 = 0.f;
  for (int i = r0 + lane; i < r1; i += 64) {
    int s = csr[i];
    float e = as2[s] + ad; e = e > 0.f ? e : NEG * e;
    float ex = __expf(e);
    float2 hv = *(const float2*)(h2 + s * 2);
    den += ex;
    a0 = fmaf(ex, hv.x, a0);
    a1 = fmaf(ex, hv.y, a1);
  }
  #pragma unroll
  for (int mm = 32; mm >= 1; mm >>= 1) {
    den += __shfl_xor(den, mm, 64);
    a0  += __shfl_xor(a0, mm, 64);
    a1  += __shfl_xor(a1, mm, 64);
  }
  if (lane == 0) {
    float o0 = a0 / den + bias2[0];
    float o1 = a1 / den + bias2[1];
    float mx = fmaxf(o0, o1);
    float lse = mx + logf(__expf(o0 - mx) + __expf(o1 - mx));
    out[n * 2 + 0] = o0 - lse;
    out[n * 2 + 1] = o1 - lse;
  }
}

extern "C" void kernel_launch(void* const* d_in, const int* in_sizes, int n_in,
                              void* d_out, int out_size, void* d_ws, size_t ws_size,
                              hipStream_t stream) {
  const float* x     = (const float*)d_in[0];
  const int*   ei    = (const int*)d_in[1];
  const float* W1    = (const float*)d_in[2];
  const float* asw1  = (const float*)d_in[3];
  const float* adw1  = (const float*)d_in[4];
  const float* bias1 = (const float*)d_in[5];
  const float* gamma = (const float*)d_in[6];
  const float* beta  = (const float*)d_in[7];
  const float* mean  = (const float*)d_in[8];
  const float* var   = (const float*)d_in[9];
  const float* W2    = (const float*)d_in[10];
  const float* asw2  = (const float*)d_in[11];
  const float* adw2  = (const float*)d_in[12];
  const float* bias2 = (const float*)d_in[13];
  float* out = (float*)d_out;

  char* ws = (char*)d_ws;
  size_t off = 0;
  auto alloc = [&](size_t bytes) {
    void* p = ws + off;
    off += (bytes + 255) & ~(size_t)255;
    return p;
  };
  signed char* h8 = (signed char*)alloc((size_t)NN * FOUT);   // 6.4 MB int8
  float* hscale = (float*)alloc((size_t)NN * 4);
  float* as1  = (float*)alloc((size_t)NN * 4 * 4);
  float* ad1  = (float*)alloc((size_t)NN * 4 * 4);
  int*   degp = (int*)alloc((size_t)NPART * DSUB * PSZ * 4);  // 1.6 MB partial histograms
  int*   offs = (int*)alloc(((size_t)NN + 1) * 4);
  int*   cur  = (int*)alloc((size_t)NN * 4);
  int*   bsum = (int*)alloc((size_t)SCB * 4);
  int*   bcur = (int*)alloc((size_t)GGRP * NPART * 16 * 4);   // 64 padded counters
  int*   csr  = (int*)alloc((size_t)(EE + NN) * 4);           // 6.6 MB
  unsigned* bkt = (unsigned*)alloc((size_t)GGRP * NPART * BCAPG * 4); // 7.7 MB
  float* h2   = (float*)alloc((size_t)NN * 2 * 4);
  float* as2  = (float*)alloc((size_t)NN * 4);
  float* ad2  = (float*)alloc((size_t)NN * 4);
  (void)ws_size; (void)in_sizes; (void)n_in; (void)out_size;

  hipMemsetAsync(bcur, 0, (size_t)GGRP * NPART * 16 * 4, stream);
  k_proj   <<<(NN + 63) / 64, 256, 0, stream>>>(x, W1, asw1, adw1, h8, hscale, as1, ad1);
  k_bucket <<<NBUCK, 256, 0, stream>>>(ei, bcur, bkt);
  k_deg    <<<NPART * DSUB, 1024, 0, stream>>>(bcur, bkt, degp);
  k_scanA  <<<SCB, 1024, 0, stream>>>(degp, cur, bsum);
  k_scanB  <<<SCB, 1024, 0, stream>>>(bsum, offs, cur);
  k_scat3  <<<NPART * DSUB, 1024, 0, stream>>>(bcur, bkt, offs, degp, csr);
  k_agg1   <<<(NN + 3) / 4, 256, 0, stream>>>(offs, csr, h8, hscale, as1, ad1, bias1, gamma, beta,
                                              mean, var, W2, asw2, adw2, h2, as2, ad2);
  k_agg2   <<<(NN + 3) / 4, 256, 0, stream>>>(offs, csr, h2, as2, ad2, bias2, out);
}

// Round 20
// 165.631 us; speedup vs baseline: 1.1659x; 1.0207x over previous
//
#include <hip/hip_runtime.h>
#include <math.h>

#define NN 50000
#define EE 1600000
#define FIN 128
#define FOUT 128   // HEADS*HID
#define NEG 0.2f
#define BNEPS 1e-5f

#define NPART 8
#define PSZ (NN / NPART)   // 6250

#define BEB 1024           // edges per bucket block (4 per thread)
#define NBUCK ((EE + BEB - 1) / BEB)   // 1563
#define GGRP 8             // writer groups (one private region per (group,partition))
#define BCAPG 30000        // capacity per (group,partition) region (mean 25k)
#define DSUB 8             // deg sub-blocks per partition (== GGRP)

// ---------------- conv1 projection + attention logits (register-tiled GEMM) ----------------
// h stored int8 with per-row scale: h[n][c] ~= q[n][c] * hscale[n].
// Block 0 also zeroes bcur (replaces the hipMemsetAsync dispatch; stream order
// guarantees completion before k_bucket).
#define XS_STRIDE 132
__global__ __launch_bounds__(256) void k_proj(const float* __restrict__ x,
    const float* __restrict__ W1, const float* __restrict__ asw, const float* __restrict__ adw,
    signed char* __restrict__ h8, float* __restrict__ hscale,
    float* __restrict__ as1, float* __restrict__ ad1, int* __restrict__ bcur) {
  __shared__ float xs[64 * XS_STRIDE];
  int t = threadIdx.x;
  int nb = blockIdx.x * 64;

  if (blockIdx.x == 0) {
    for (int i = t; i < GGRP * NPART * 16; i += 256) bcur[i] = 0;
  }

  #pragma unroll
  for (int j = 0; j < 8; ++j) {
    int idx = t + 256 * j;
    int r = idx >> 5;
    int c4 = idx & 31;
    int n = nb + r; if (n >= NN) n = NN - 1;
    float4 v = *(const float4*)(x + (size_t)n * FIN + c4 * 4);
    *(float4*)(&xs[r * XS_STRIDE + c4 * 4]) = v;
  }
  __syncthreads();

  int cg = t & 15;
  int ng = t >> 4;
  int c0 = cg * 8;

  float acc[4][8];
  #pragma unroll
  for (int i = 0; i < 4; ++i)
    #pragma unroll
    for (int j = 0; j < 8; ++j) acc[i][j] = 0.f;

  for (int k0 = 0; k0 < FIN; k0 += 4) {
    float xr[4][4];
    #pragma unroll
    for (int i = 0; i < 4; ++i)
      *(float4*)xr[i] = *(const float4*)&xs[(ng * 4 + i) * XS_STRIDE + k0];
    #pragma unroll
    for (int kk = 0; kk < 4; ++kk) {
      float4 w0 = *(const float4*)(W1 + (k0 + kk) * FOUT + c0);
      float4 w1 = *(const float4*)(W1 + (k0 + kk) * FOUT + c0 + 4);
      float wv[8] = {w0.x, w0.y, w0.z, w0.w, w1.x, w1.y, w1.z, w1.w};
      #pragma unroll
      for (int i = 0; i < 4; ++i) {
        float xv = xr[i][kk];
        #pragma unroll
        for (int j = 0; j < 8; ++j) acc[i][j] = fmaf(xv, wv[j], acc[i][j]);
      }
    }
  }

  int head = cg >> 2;
  float vs[4], vd[4], rmax[4];
  #pragma unroll
  for (int i = 0; i < 4; ++i) {
    float s = 0.f, d = 0.f, m = 0.f;
    #pragma unroll
    for (int j = 0; j < 8; ++j) {
      s = fmaf(acc[i][j], asw[c0 + j], s);
      d = fmaf(acc[i][j], adw[c0 + j], d);
      m = fmaxf(m, fabsf(acc[i][j]));
    }
    vs[i] = s; vd[i] = d; rmax[i] = m;
  }
  #pragma unroll
  for (int i = 0; i < 4; ++i) {
    rmax[i] = fmaxf(rmax[i], __shfl_xor(rmax[i], 1, 64));
    rmax[i] = fmaxf(rmax[i], __shfl_xor(rmax[i], 2, 64));
    rmax[i] = fmaxf(rmax[i], __shfl_xor(rmax[i], 4, 64));
    rmax[i] = fmaxf(rmax[i], __shfl_xor(rmax[i], 8, 64));
  }
  #pragma unroll
  for (int i = 0; i < 4; ++i) {
    int n = nb + ng * 4 + i;
    if (n >= NN) continue;
    float rm = fmaxf(rmax[i], 1e-30f);
    float inv = 127.f / rm;
    unsigned b[8];
    #pragma unroll
    for (int j = 0; j < 8; ++j) {
      float qf = fminf(127.f, fmaxf(-127.f, rintf(acc[i][j] * inv)));
      b[j] = (unsigned)((int)qf) & 0xffu;
    }
    uint2 pk;
    pk.x = b[0] | (b[1] << 8) | (b[2] << 16) | (b[3] << 24);
    pk.y = b[4] | (b[5] << 8) | (b[6] << 16) | (b[7] << 24);
    *(uint2*)(h8 + (size_t)n * FOUT + c0) = pk;
    if (cg == 0) hscale[n] = rm / 127.f;
  }
  #pragma unroll
  for (int i = 0; i < 4; ++i) {
    vs[i] += __shfl_xor(vs[i], 1, 64); vs[i] += __shfl_xor(vs[i], 2, 64);
    vd[i] += __shfl_xor(vd[i], 1, 64); vd[i] += __shfl_xor(vd[i], 2, 64);
  }
  if ((cg & 3) == 0) {
    #pragma unroll
    for (int i = 0; i < 4; ++i) {
      int n = nb + ng * 4 + i;
      if (n < NN) { as1[n * 4 + head] = vs[i]; ad1[n * 4 + head] = vd[i]; }
    }
  }
}

// pass A: bucket edges by dst-range. 64 private regions (g,p).
__global__ __launch_bounds__(256) void k_bucket(const int* __restrict__ ei,
    int* __restrict__ bcur, unsigned* __restrict__ bkt) {
  __shared__ int lcnt[NPART];
  __shared__ int gbase[NPART];
  int t = threadIdx.x;
  int g = blockIdx.x & (GGRP - 1);
  if (t < NPART) lcnt[t] = 0;
  __syncthreads();
  int e0 = blockIdx.x * BEB;
  int part[4]; int lslot[4]; unsigned pk[4];
  #pragma unroll
  for (int j = 0; j < 4; ++j) {
    int i = e0 + j * 256 + t;
    if (i < EE) {
      int s = ei[i];
      int d = ei[EE + i];
      int p = d / PSZ;
      part[j] = p;
      pk[j] = (unsigned)s | ((unsigned)(d - p * PSZ) << 17);
      lslot[j] = atomicAdd(&lcnt[p], 1);
    } else part[j] = -1;
  }
  __syncthreads();
  if (t < NPART) gbase[t] = atomicAdd(&bcur[(g * NPART + t) * 16], lcnt[t]);
  __syncthreads();
  #pragma unroll
  for (int j = 0; j < 4; ++j) {
    if (part[j] >= 0)
      bkt[(size_t)(g * NPART + part[j]) * BCAPG + gbase[part[j]] + lslot[j]] = pk[j];
  }
}

// degree: block (g,p) LDS-histograms region (g,p). No global atomics.
__global__ __launch_bounds__(1024) void k_deg(const int* __restrict__ bcur,
    const unsigned* __restrict__ bkt, int* __restrict__ degp) {
  __shared__ int lh[PSZ];               // 25 KB
  int t = threadIdx.x;
  int part = blockIdx.x & (NPART - 1);
  int g    = blockIdx.x >> 3;
  for (int i = t; i < PSZ; i += 1024) lh[i] = 0;
  __syncthreads();
  int cnt = bcur[(g * NPART + part) * 16];
  const unsigned* b = bkt + (size_t)(g * NPART + part) * BCAPG;
  for (int i = t; i < cnt; i += 1024)
    atomicAdd(&lh[b[i] >> 17], 1);
  __syncthreads();
  int* dst = degp + ((size_t)part * DSUB + g) * PSZ;
  for (int i = t; i < PSZ; i += 1024) dst[i] = lh[i];
}

// Fused scan + scatter: block (g,p) computes partition base from bcur, the
// within-partition node prefix (chunked + block scan), writes offs (g==0 only),
// seeds lcur = offs + prefix_{g'<g} degp, places its region's edges, and (g==7)
// appends self-loops. Zero global atomics; single-writer csr lines per partition.
__global__ __launch_bounds__(1024) void k_scat4(const int* __restrict__ bcur,
    const unsigned* __restrict__ bkt, const int* __restrict__ degp,
    int* __restrict__ offs, int* __restrict__ csr) {
  __shared__ int lcur[PSZ];             // 25 KB
  __shared__ int sums[1024];
  __shared__ int sb[GGRP * NPART];
  int t = threadIdx.x;
  int p = blockIdx.x & (NPART - 1);
  int g = blockIdx.x >> 3;
  if (t < GGRP * NPART) sb[t] = bcur[t * 16];
  __syncthreads();

  int base_p = 0;
  for (int pp = 0; pp < p; ++pp) {
    int s = PSZ;
    for (int gg = 0; gg < GGRP; ++gg) s += sb[gg * NPART + pp];
    base_p += s;
  }

  const int CH = 7;                     // ceil(6250/1024)
  int n0 = t * CH;
  int tsum = 0;
  for (int i = 0; i < CH; ++i) {
    int idx = n0 + i;
    if (idx < PSZ) {
      int v = 1;
      for (int gg = 0; gg < GGRP; ++gg)
        v += degp[((size_t)p * DSUB + gg) * PSZ + idx];
      tsum += v;
    }
  }
  sums[t] = tsum; __syncthreads();
  for (int off = 1; off < 1024; off <<= 1) {
    int u = (t >= off) ? sums[t - off] : 0;
    __syncthreads();
    sums[t] += u;
    __syncthreads();
  }
  int run = base_p + ((t == 0) ? 0 : sums[t - 1]);
  for (int i = 0; i < CH; ++i) {
    int idx = n0 + i;
    if (idx < PSZ) {
      int v = 1, pre = 0;
      for (int gg = 0; gg < GGRP; ++gg) {
        int d = degp[((size_t)p * DSUB + gg) * PSZ + idx];
        v += d;
        if (gg < g) pre += d;
      }
      if (g == 0) offs[p * PSZ + idx] = run;
      lcur[idx] = run + pre;
      run += v;
    }
  }
  if (g == 0 && p == NPART - 1 && t == 1023)
    offs[NN] = base_p + sums[1023];     // total = EE + NN
  __syncthreads();

  int cnt = sb[g * NPART + p];
  const unsigned* b = bkt + (size_t)(g * NPART + p) * BCAPG;
  for (int i = t; i < cnt; i += 1024) {
    unsigned v = b[i];
    int pos = atomicAdd(&lcur[v >> 17], 1);
    csr[pos] = (int)(v & 0x1ffffu);
  }
  if (g == DSUB - 1) {
    __syncthreads();
    for (int i = t; i < PSZ; i += 1024)
      csr[lcur[i]] = p * PSZ + i;       // self loop: last slot of each segment
  }
}

// ---------------- conv1 aggregation + BN + leaky + conv2 projection ----------------
// Half-split wave: 32 sublanes x 4 int8 channels; two wave halves process two
// DIFFERENT edges per body step. slds stores pre-multiplied byte row offset.
__global__ __launch_bounds__(256) void k_agg1(
    const int* __restrict__ offs, const int* __restrict__ csr,
    const signed char* __restrict__ h8, const float* __restrict__ hscale,
    const float* __restrict__ as1, const float* __restrict__ ad1,
    const float* __restrict__ bias1, const float* __restrict__ gamma, const float* __restrict__ beta,
    const float* __restrict__ mean, const float* __restrict__ var,
    const float* __restrict__ W2, const float* __restrict__ asw2, const float* __restrict__ adw2,
    float* __restrict__ h2, float* __restrict__ as2, float* __restrict__ ad2) {
  __shared__ int   slds[4][32];
  __shared__ float wlds[4][32][4];
  int wid = threadIdx.x >> 6;
  int lane = threadIdx.x & 63;
  int n = blockIdx.x * 4 + wid;
  if (n >= NN) return;
  int r0 = offs[n], r1 = offs[n + 1];
  int l  = lane & 31;
  int hf = lane >> 5;
  int hh = l >> 3;
  int l4 = l * 4;
  const signed char* hpb = h8;
  float2 adv = *(const float2*)(ad1 + n * 4 + hf * 2);

  float acc0 = 0.f, acc1 = 0.f, acc2 = 0.f, acc3 = 0.f;
  float denp0 = 0.f, denp1 = 0.f;

#define AGG_PRE(IDX, PRED)                                         \
  {                                                                \
    int sv = csr[(IDX)];                                           \
    float hs = hscale[sv];                                         \
    float2 av = *(const float2*)(as1 + sv * 4 + hf * 2);           \
    float e0 = av.x + adv.x; e0 = e0 > 0.f ? e0 : NEG * e0;        \
    float e1 = av.y + adv.y; e1 = e1 > 0.f ? e1 : NEG * e1;        \
    float ex0 = __expf(e0), ex1 = __expf(e1);                      \
    float w0 = ex0 * hs, w1 = ex1 * hs;                            \
    if (PRED) { denp0 += ex0; denp1 += ex1; }                      \
    wlds[wid][l][hf * 2]     = (PRED) ? w0 : 0.f;                  \
    wlds[wid][l][hf * 2 + 1] = (PRED) ? w1 : 0.f;                  \
    if (hf == 0) slds[wid][l] = sv * FOUT;                         \
  }

#define AGG_BODY(J)                                                \
  {                                                                \
    int soff = slds[wid][hf * 16 + (J)];                           \
    float w = wlds[wid][hf * 16 + (J)][hh];                        \
    unsigned pv = *(const unsigned*)(hpb + soff + l4);             \
    int q0 = ((int)(pv << 24)) >> 24;                              \
    int q1 = ((int)(pv << 16)) >> 24;                              \
    int q2 = ((int)(pv << 8)) >> 24;                               \
    int q3 = ((int)pv) >> 24;                                      \
    acc0 = fmaf(w, (float)q0, acc0);                               \
    acc1 = fmaf(w, (float)q1, acc1);                               \
    acc2 = fmaf(w, (float)q2, acc2);                               \
    acc3 = fmaf(w, (float)q3, acc3);                               \
  }

  int base = r0;
  for (; base + 32 <= r1; base += 32) {
    AGG_PRE(base + l, true)
    #pragma unroll
    for (int j = 0; j < 16; ++j) AGG_BODY(j)
  }
  int m = r1 - base;
  if (m > 0) {
    AGG_PRE(base + (l < m ? l : m - 1), l < m)
    int jmax = m < 16 ? m : 16;
    for (int j = 0; j < jmax; ++j) AGG_BODY(j)
  }

  acc0 += __shfl_xor(acc0, 32, 64);
  acc1 += __shfl_xor(acc1, 32, 64);
  acc2 += __shfl_xor(acc2, 32, 64);
  acc3 += __shfl_xor(acc3, 32, 64);

  #pragma unroll
  for (int mm = 16; mm >= 1; mm >>= 1) {
    denp0 += __shfl_xor(denp0, mm, 64);
    denp1 += __shfl_xor(denp1, mm, 64);
  }
  float dOA = __shfl_xor(denp0, 32, 64);
  float dOB = __shfl_xor(denp1, 32, 64);
  float den0 = hf ? dOA : denp0;
  float den1 = hf ? dOB : denp1;
  float den2 = hf ? denp0 : dOA;
  float den3 = hf ? denp1 : dOB;
  float den = (hh == 0) ? den0 : (hh == 1) ? den1 : (hh == 2) ? den2 : den3;

  int c0 = l * 4;
  float inv = 1.f / den;
  float4 bi = *(const float4*)(bias1 + c0);
  float4 ga = *(const float4*)(gamma + c0);
  float4 be = *(const float4*)(beta + c0);
  float4 mu = *(const float4*)(mean + c0);
  float4 va = *(const float4*)(var + c0);
  float o0 = acc0 * inv + bi.x;
  float o1 = acc1 * inv + bi.y;
  float o2 = acc2 * inv + bi.z;
  float o3 = acc3 * inv + bi.w;
  o0 = ga.x * (o0 - mu.x) * rsqrtf(va.x + BNEPS) + be.x;
  o1 = ga.y * (o1 - mu.y) * rsqrtf(va.y + BNEPS) + be.y;
  o2 = ga.z * (o2 - mu.z) * rsqrtf(va.z + BNEPS) + be.z;
  o3 = ga.w * (o3 - mu.w) * rsqrtf(va.w + BNEPS) + be.w;
  o0 = o0 > 0.f ? o0 : NEG * o0;
  o1 = o1 > 0.f ? o1 : NEG * o1;
  o2 = o2 > 0.f ? o2 : NEG * o2;
  o3 = o3 > 0.f ? o3 : NEG * o3;

  float p0 = o0 * W2[(c0 + 0) * 2 + 0] + o1 * W2[(c0 + 1) * 2 + 0]
           + o2 * W2[(c0 + 2) * 2 + 0] + o3 * W2[(c0 + 3) * 2 + 0];
  float p1 = o0 * W2[(c0 + 0) * 2 + 1] + o1 * W2[(c0 + 1) * 2 + 1]
           + o2 * W2[(c0 + 2) * 2 + 1] + o3 * W2[(c0 + 3) * 2 + 1];
  #pragma unroll
  for (int mm = 16; mm >= 1; mm >>= 1) {
    p0 += __shfl_xor(p0, mm, 64);
    p1 += __shfl_xor(p1, mm, 64);
  }
  if (lane == 0) {
    h2[n * 2 + 0] = p0;
    h2[n * 2 + 1] = p1;
    as2[n] = p0 * asw2[0] + p1 * asw2[1];
    ad2[n] = p0 * adw2[0] + p1 * adw2[1];
  }
}

// ---------------- conv2 aggregation (no-max softmax) + bias + log_softmax ----------------
__global__ __launch_bounds__(256) void k_agg2(
    const int* __restrict__ offs, const int* __restrict__ csr,
    const float* __restrict__ h2, const float* __restrict__ as2, const float* __restrict__ ad2,
    const float* __restrict__ bias2, float* __restrict__ out) {
  int wid = threadIdx.x >> 6;
  int lane = threadIdx.x & 63;
  int n = blockIdx.x * 4 + wid;
  if (n >= NN) return;
  int r0 = offs[n], r1 = offs[n + 1];
  float ad = ad2[n];

  float den = 0.f, a0 = 0.f, a1 = 0.f;
  for (int i = r0 + lane; i < r1; i += 64) {
    int s = csr[i];
    float e = as2[s] + ad; e = e > 0.f ? e : NEG * e;
    float ex = __expf(e);
    float2 hv = *(const float2*)(h2 + s * 2);
    den += ex;
    a0 = fmaf(ex, hv.x, a0);
    a1 = fmaf(ex, hv.y, a1);
  }
  #pragma unroll
  for (int mm = 32; mm >= 1; mm >>= 1) {
    den += __shfl_xor(den, mm, 64);
    a0  += __shfl_xor(a0, mm, 64);
    a1  += __shfl_xor(a1, mm, 64);
  }
  if (lane == 0) {
    float o0 = a0 / den + bias2[0];
    float o1 = a1 / den + bias2[1];
    float mx = fmaxf(o0, o1);
    float lse = mx + logf(__expf(o0 - mx) + __expf(o1 - mx));
    out[n * 2 + 0] = o0 - lse;
    out[n * 2 + 1] = o1 - lse;
  }
}

extern "C" void kernel_launch(void* const* d_in, const int* in_sizes, int n_in,
                              void* d_out, int out_size, void* d_ws, size_t ws_size,
                              hipStream_t stream) {
  const float* x     = (const float*)d_in[0];
  const int*   ei    = (const int*)d_in[1];
  const float* W1    = (const float*)d_in[2];
  const float* asw1  = (const float*)d_in[3];
  const float* adw1  = (const float*)d_in[4];
  const float* bias1 = (const float*)d_in[5];
  const float* gamma = (const float*)d_in[6];
  const float* beta  = (const float*)d_in[7];
  const float* mean  = (const float*)d_in[8];
  const float* var   = (const float*)d_in[9];
  const float* W2    = (const float*)d_in[10];
  const float* asw2  = (const float*)d_in[11];
  const float* adw2  = (const float*)d_in[12];
  const float* bias2 = (const float*)d_in[13];
  float* out = (float*)d_out;

  char* ws = (char*)d_ws;
  size_t off = 0;
  auto alloc = [&](size_t bytes) {
    void* p = ws + off;
    off += (bytes + 255) & ~(size_t)255;
    return p;
  };
  signed char* h8 = (signed char*)alloc((size_t)NN * FOUT);   // 6.4 MB int8
  float* hscale = (float*)alloc((size_t)NN * 4);
  float* as1  = (float*)alloc((size_t)NN * 4 * 4);
  float* ad1  = (float*)alloc((size_t)NN * 4 * 4);
  int*   degp = (int*)alloc((size_t)NPART * DSUB * PSZ * 4);  // 1.6 MB partial histograms
  int*   offs = (int*)alloc(((size_t)NN + 1) * 4);
  int*   bcur = (int*)alloc((size_t)GGRP * NPART * 16 * 4);   // 64 padded counters
  int*   csr  = (int*)alloc((size_t)(EE + NN) * 4);           // 6.6 MB
  unsigned* bkt = (unsigned*)alloc((size_t)GGRP * NPART * BCAPG * 4); // 7.7 MB
  float* h2   = (float*)alloc((size_t)NN * 2 * 4);
  float* as2  = (float*)alloc((size_t)NN * 4);
  float* ad2  = (float*)alloc((size_t)NN * 4);
  (void)ws_size; (void)in_sizes; (void)n_in; (void)out_size;

  k_proj   <<<(NN + 63) / 64, 256, 0, stream>>>(x, W1, asw1, adw1, h8, hscale, as1, ad1, bcur);
  k_bucket <<<NBUCK, 256, 0, stream>>>(ei, bcur, bkt);
  k_deg    <<<NPART * DSUB, 1024, 0, stream>>>(bcur, bkt, degp);
  k_scat4  <<<NPART * DSUB, 1024, 0, stream>>>(bcur, bkt, degp, offs, csr);
  k_agg1   <<<(NN + 3) / 4, 256, 0, stream>>>(offs, csr, h8, hscale, as1, ad1, bias1, gamma, beta,
                                              mean, var, W2, asw2, adw2, h2, as2, ad2);
  k_agg2   <<<(NN + 3) / 4, 256, 0, stream>>>(offs, csr, h2, as2, ad2, bias2, out);
}